// Round 5
// baseline (469.709 us; speedup 1.0000x reference)
//
#include <hip/hip_runtime.h>
#include <math.h>

#define SCALE 0.36067376022224085f  // 0.25 * log2(e)

typedef __attribute__((ext_vector_type(8))) short short8;
typedef __attribute__((ext_vector_type(4))) float f32x4;

// ---- bf16 pack offsets (ushort elements) ----
#define G1H 0
#define G1L 512
#define WV1H 1024
#define WV1L 3072
#define WV2H 5120
#define WV2L 7168
#define WKT2H 9216
#define WKT2L 11264
#define WQ2H 13312
#define WQ2L 17408
#define WO1H 21504
#define WO1L 25600
#define WO2H 29696
#define WO2L 33792
#define F1H 37888
#define F1L 46080
#define F2H 54272
#define F2L 62464
#define OP1H 70656
#define OP1L 72704
// ---- fp32 temp offsets (float elements) ----
#define WKF1T 37376
#define WKF2T 39424
#define WVF1T 41472
#define WVF2T 43520
#define Q1T   45568
#define BV1T  45760   // 128 floats (bvf1, bvf2)

#define WSYNC() do { asm volatile("s_waitcnt lgkmcnt(0)" ::: "memory"); __builtin_amdgcn_wave_barrier(); } while (0)

__device__ __forceinline__ unsigned short f2bf(float x) {
  unsigned u = __builtin_bit_cast(unsigned, x);
  return (unsigned short)((u + 0x7fffu + ((u >> 16) & 1u)) >> 16);
}
__device__ __forceinline__ float bf2f(unsigned short h) {
  unsigned u = ((unsigned)h) << 16;
  return __builtin_bit_cast(float, u);
}
// build hi/lo bf16 A-frag from 8 consecutive fp32 in LDS (16B-aligned)
__device__ __forceinline__ void lds_frag(const float* row, int koff, short8& fh, short8& fl) {
  const float4 a = *(const float4*)(row + koff);
  const float4 b = *(const float4*)(row + koff + 4);
  float v[8] = {a.x, a.y, a.z, a.w, b.x, b.y, b.z, b.w};
#pragma unroll
  for (int j = 0; j < 8; ++j) {
    unsigned short h = f2bf(v[j]);
    fh[j] = (short)h;
    fl[j] = (short)f2bf(v[j] - bf2f(h));
  }
}
__device__ __forceinline__ short8 ldg_frag(const unsigned short* base, int idx) {
  return __builtin_bit_cast(short8, *(const float4*)(base + idx));
}
#define MFMA3(acc, ah, al, bh, bl)                                      \
  acc = __builtin_amdgcn_mfma_f32_16x16x32_bf16(ah, bh, acc, 0, 0, 0);  \
  acc = __builtin_amdgcn_mfma_f32_16x16x32_bf16(ah, bl, acc, 0, 0, 0);  \
  acc = __builtin_amdgcn_mfma_f32_16x16x32_bf16(al, bh, acc, 0, 0, 0);

struct Params {
  const float *tl, *tr, *qemb, *ip_w1, *ip_b1;
  const float *bq2, *bo1, *bo2, *fb1, *fb2, *opb1, *opw2, *opb2;
  const float *n1g, *n1b, *n2g, *n2b, *n3g, *n3b;
  const float* wsf;
  const unsigned short* wsb;
  float* out;
};

// ---------- prepA: fp32 folds ----------
__global__ void prepA_kernel(const float* ip_w2, const float* ip_b2,
                             const float* wk1, const float* wk2,
                             const float* wv1, const float* wv2,
                             const float* bv1, const float* bv2,
                             const float* qemb, const float* wq1, const float* bq1,
                             float* wsf) {
  const int bid = blockIdx.x, tid = threadIdx.x;
  if (bid < 32) {
    const int e = bid * 256 + tid;       // 0..8191
    const int mat = e >> 11, rem = e & 2047;
    const int j = rem >> 6, c = rem & 63;
    const float* W = (mat == 0) ? wk1 : (mat == 1) ? wk2 : (mat == 2) ? wv1 : wv2;
    float acc = 0.f;
    for (int m = 0; m < 64; ++m) acc = fmaf(ip_w2[j * 64 + m], W[m * 64 + c], acc);
    wsf[WKF1T + e] = acc;
  } else if (bid == 32) {
    if (tid < 192) {
      const int q = tid >> 6, d = tid & 63;
      float acc = bq1[d];
      for (int e = 0; e < 64; ++e) acc = fmaf(qemb[q * 64 + e], wq1[e * 64 + d], acc);
      wsf[Q1T + tid] = acc;
    }
  } else {
    if (tid < 128) {
      const int lyr = tid >> 6, d = tid & 63;
      const float* bv = lyr ? bv2 : bv1;
      const float* wv = lyr ? wv2 : wv1;
      float acc = bv[d];
      for (int m = 0; m < 64; ++m) acc = fmaf(ip_b2[m], wv[m * 64 + d], acc);
      wsf[BV1T + tid] = acc;
    }
  }
}

// ---------- prepB: pack weights into MFMA B-fragment layout (hi/lo bf16) ----------
// B-frag: lane l holds B[k = 32*kt + 8*(l>>4) + j][n = 16*nt + (l&15)], j=0..7
__global__ void prepB_kernel(float* wsf, unsigned short* wsb,
                             const float* wq2, const float* wo1, const float* wo2,
                             const float* fw1, const float* fw2, const float* opw1) {
  const int bid = blockIdx.x, tid = threadIdx.x;  // 512 threads
  if (bid == 0) {
    __shared__ float g1f[32][16];
    {
      const int j = tid >> 4, col = tid & 15;
      float acc = 0.f;
      if (col < 12) {
        const int h = (col * 11) >> 5, q = col - 3 * h;
        for (int d = 0; d < 16; ++d)
          acc = fmaf(wsf[WKF1T + j * 64 + h * 16 + d], wsf[Q1T + q * 64 + h * 16 + d], acc);
        acc *= SCALE;
      }
      g1f[j][col] = acc;
    }
    __syncthreads();
    {
      const int e = tid, j8 = e & 7, ln = (e >> 3) & 63;
      const int k = (ln >> 4) * 8 + j8, n = ln & 15;
      const float val = g1f[k][n];
      const unsigned short h = f2bf(val);
      wsb[G1H + e] = h;
      wsb[G1L + e] = f2bf(val - bf2f(h));
    }
    return;
  }
  const int pe = (bid - 1) * 512 + tid;  // 0..36863
  const int j8 = pe & 7, ln = (pe >> 3) & 63;
  const int krow = (ln >> 4) * 8 + j8, ncol = ln & 15;
  float val;
  int hOff, lOff, loc;
  if (pe < 2048) {          // wvf1: K32 N64
    loc = pe; const int nt = (loc >> 9) & 3;
    val = wsf[WVF1T + krow * 64 + nt * 16 + ncol];
    hOff = WV1H; lOff = WV1L;
  } else if (pe < 4096) {   // wvf2
    loc = pe - 2048; const int nt = (loc >> 9) & 3;
    val = wsf[WVF2T + krow * 64 + nt * 16 + ncol];
    hOff = WV2H; lOff = WV2L;
  } else if (pe < 6144) {   // wkT2: K64 N32, transpose of Wkf2 [32][64], *SCALE
    loc = pe - 4096; const int nt = (loc >> 9) & 1, kt = (loc >> 10) & 1;
    val = SCALE * wsf[WKF2T + (nt * 16 + ncol) * 64 + kt * 32 + krow];
    hOff = WKT2H; lOff = WKT2L;
  } else if (pe < 10240) {  // wq2: K64 N64
    loc = pe - 6144; const int nt = (loc >> 9) & 3, kt = (loc >> 11) & 1;
    val = wq2[(kt * 32 + krow) * 64 + nt * 16 + ncol];
    hOff = WQ2H; lOff = WQ2L;
  } else if (pe < 14336) {  // wo1
    loc = pe - 10240; const int nt = (loc >> 9) & 3, kt = (loc >> 11) & 1;
    val = wo1[(kt * 32 + krow) * 64 + nt * 16 + ncol];
    hOff = WO1H; lOff = WO1L;
  } else if (pe < 18432) {  // wo2
    loc = pe - 14336; const int nt = (loc >> 9) & 3, kt = (loc >> 11) & 1;
    val = wo2[(kt * 32 + krow) * 64 + nt * 16 + ncol];
    hOff = WO2H; lOff = WO2L;
  } else if (pe < 26624) {  // ffn_w1: K64 N128
    loc = pe - 18432; const int nt = (loc >> 9) & 7, kt = (loc >> 12) & 1;
    val = fw1[(kt * 32 + krow) * 128 + nt * 16 + ncol];
    hOff = F1H; lOff = F1L;
  } else if (pe < 34816) {  // ffn_w2: K128 N64
    loc = pe - 26624; const int nt = (loc >> 9) & 3, kt = (loc >> 11) & 3;
    val = fw2[(kt * 32 + krow) * 64 + nt * 16 + ncol];
    hOff = F2H; lOff = F2L;
  } else {                  // op_w1: K64 N32
    loc = pe - 34816; const int nt = (loc >> 9) & 1, kt = (loc >> 10) & 1;
    val = opw1[(kt * 32 + krow) * 32 + nt * 16 + ncol];
    hOff = OP1H; lOff = OP1L;
  }
  const unsigned short h = f2bf(val);
  wsb[hOff + loc] = h;
  wsb[lOff + loc] = f2bf(val - bf2f(h));
}

// LN over 64 cols held as [nt 0..3][reg 0..3] per lane (cols nt*16+l15, rows l4*4+reg)
__device__ __forceinline__ void ln_write(float v[4][4], const float* gam, const float* bet,
                                         float xs[][68], float xq[4][4], int l15, int l4) {
  float g4[4], b4[4];
#pragma unroll
  for (int nt = 0; nt < 4; ++nt) { g4[nt] = gam[nt * 16 + l15]; b4[nt] = bet[nt * 16 + l15]; }
#pragma unroll
  for (int reg = 0; reg < 4; ++reg) {
    float s = v[0][reg] + v[1][reg] + v[2][reg] + v[3][reg];
    s += __shfl_xor(s, 1); s += __shfl_xor(s, 2); s += __shfl_xor(s, 4); s += __shfl_xor(s, 8);
    const float mu = s * 0.015625f;
    float d[4];
#pragma unroll
    for (int nt = 0; nt < 4; ++nt) d[nt] = v[nt][reg] - mu;
    float s2 = d[0]*d[0] + d[1]*d[1] + d[2]*d[2] + d[3]*d[3];
    s2 += __shfl_xor(s2, 1); s2 += __shfl_xor(s2, 2); s2 += __shfl_xor(s2, 4); s2 += __shfl_xor(s2, 8);
    const float inv = rsqrtf(fmaf(s2, 0.015625f, 1e-5f));
    const int r = l4 * 4 + reg;
#pragma unroll
    for (int nt = 0; nt < 4; ++nt) {
      const float xn = fmaf(d[nt] * inv, g4[nt], b4[nt]);
      xq[nt][reg] = xn;
      if (r < 6) xs[r][nt * 16 + l15] = xn;
    }
  }
}

__global__ __launch_bounds__(256) void planner_kernel(Params p) {
  const int w = threadIdx.x >> 6, l = threadIdx.x & 63;
  const int l15 = l & 15, l4 = l >> 4;
  const unsigned short* wb = p.wsb;

  __shared__ __align__(16) float a_s[4][64][36];       // acts (rows item*32+t); later f overlay
  __shared__ __align__(16) float att_s[4][2][12][24];
  __shared__ __align__(16) float g2_s[4][2][12][36];
  __shared__ __align__(16) float x_s[4][6][68];
  __shared__ __align__(16) float o_s[4][6][68];        // o / q2 / y1
  __shared__ float pts_s[4][2][40];
  __shared__ float qemb_s[192];
  __shared__ float nrm_s[6][64];
  __shared__ float bias4_s[4][64];   // bo1, bo2, bq2, fb2
  __shared__ float fb1_s[128];
  __shared__ float opb1_s[32];
  __shared__ float opw2_s[64];
  __shared__ float opb2_s[2];
  __shared__ float bvf_s[2][64];
  __shared__ float ipw_s[2][32];
  __shared__ float ipb_s[32];

  // ---- block preamble: stage shared read-only vectors ----
  {
    const int t = threadIdx.x;
    if (t < 192) qemb_s[t] = p.qemb[t];
    for (int e = t; e < 384; e += 256) {
      const int k = e >> 6, d = e & 63;
      float v = (k == 0) ? p.n1g[d] : (k == 1) ? p.n1b[d] : (k == 2) ? p.n2g[d]
              : (k == 3) ? p.n2b[d] : (k == 4) ? p.n3g[d] : p.n3b[d];
      nrm_s[k][d] = v;
    }
    {
      const int k = t >> 6, d = t & 63;
      bias4_s[k][d] = (k == 0) ? p.bo1[d] : (k == 1) ? p.bo2[d] : (k == 2) ? p.bq2[d] : p.fb2[d];
    }
    if (t < 128) fb1_s[t] = p.fb1[t];
    if (t < 32) opb1_s[t] = p.opb1[t];
    if (t < 64) opw2_s[t] = p.opw2[t];
    if (t < 2) opb2_s[t] = p.opb2[t];
    if (t < 128) bvf_s[t >> 6][t & 63] = p.wsf[BV1T + t];
    if (t < 64) ipw_s[t >> 5][t & 31] = p.ip_w1[t];
    if (t < 32) ipb_s[t] = p.ip_b1[t];
  }
  __syncthreads();

  float (*aw)[36] = a_s[w];
  const int itemBase = blockIdx.x * 8 + w * 2;

  // ---- P1: points -> activations a (+ zero pads) ----
#pragma unroll
  for (int pass = 0; pass < 2; ++pass) {
    const int idx = pass * 64 + l;
    if (idx < 80) {
      const int i = idx / 40, r = idx - 40 * i;
      pts_s[w][i][r] = (r < 20) ? p.tl[(itemBase + i) * 20 + r] : p.tr[(itemBase + i) * 20 + r - 20];
    }
  }
  WSYNC();
  {
    const int i = l >> 5, j = l & 31;
    const float w0 = ipw_s[0][j], w1 = ipw_s[1][j], b = ipb_s[j];
#pragma unroll
    for (int tt = 0; tt < 20; ++tt) {
      const float h = fmaf(pts_s[w][i][2 * tt], w0, fmaf(pts_s[w][i][2 * tt + 1], w1, b));
      aw[i * 32 + tt][j] = fmaxf(h, 0.f);
    }
#pragma unroll
    for (int tt = 20; tt < 32; ++tt) aw[i * 32 + tt][j] = 0.f;
  }
  for (int e = l; e < 96; e += 64) {
    const int i = e / 48, rem = e - 48 * i;
    att_s[w][i][rem >> 2][20 + (rem & 3)] = 0.f;
  }
  WSYNC();

  float xq1[4][4], xq2[4][4], xq3[4][4];

  // ================= LAYER LOOP (manually specialized) =================
#pragma unroll 1
  for (int lyr = 0; lyr < 2; ++lyr) {
    // ---- scores: S = a @ g  (g1 pack for lyr0; g2 from LDS for lyr1) ----
    {
      f32x4 S[4];
      short8 bh, bl;
      if (lyr == 0) { bh = ldg_frag(wb + G1H, l * 8); bl = ldg_frag(wb + G1L, l * 8); }
#pragma unroll
      for (int mt = 0; mt < 4; ++mt) {
        if (lyr == 1 && (mt & 1) == 0)
          lds_frag(&g2_s[w][mt >> 1][min(l15, 11)][0], l4 * 8, bh, bl);
        short8 ah, al;
        lds_frag(&aw[mt * 16 + l15][0], l4 * 8, ah, al);
        S[mt] = (f32x4){0.f, 0.f, 0.f, 0.f};
        MFMA3(S[mt], ah, al, bh, bl);
      }
      // softmax per item (exp2 domain; SCALE folded into g)
#pragma unroll
      for (int i = 0; i < 2; ++i) {
        float sv[8];
        float m = -3.0e38f;
#pragma unroll
        for (int mo = 0; mo < 2; ++mo)
#pragma unroll
          for (int r = 0; r < 4; ++r) {
            float s = S[i * 2 + mo][r];
            if (mo == 1 && l4 != 0) s = -3.0e38f;
            sv[mo * 4 + r] = s;
            m = fmaxf(m, s);
          }
        m = fmaxf(m, __shfl_xor(m, 16)); m = fmaxf(m, __shfl_xor(m, 32));
        float sum = 0.f;
#pragma unroll
        for (int k = 0; k < 8; ++k) { sv[k] = exp2f(sv[k] - m); sum += sv[k]; }
        sum += __shfl_xor(sum, 16); sum += __shfl_xor(sum, 32);
        const float inv = 1.f / sum;
#pragma unroll
        for (int mo = 0; mo < 2; ++mo)
#pragma unroll
          for (int r = 0; r < 4; ++r) {
            const int tt = mo * 16 + l4 * 4 + r;
            if (l15 < 12 && tt < 20) att_s[w][i][l15][tt] = sv[mo * 4 + r] * inv;
          }
      }
    }
    WSYNC();

    // ---- V-GEMM + fused AV ----
    {
      const int vh = lyr ? WV2H : WV1H, vl = lyr ? WV2L : WV1L;
      float op[2][3][4];
#pragma unroll
      for (int i = 0; i < 2; ++i)
#pragma unroll
        for (int q = 0; q < 3; ++q)
#pragma unroll
          for (int nt = 0; nt < 4; ++nt) op[i][q][nt] = 0.f;
#pragma unroll
      for (int mt = 0; mt < 4; ++mt) {
        short8 ah, al;
        lds_frag(&aw[mt * 16 + l15][0], l4 * 8, ah, al);
        const int i = mt >> 1;
        const int tb = min((mt & 1) * 16 + l4 * 4, 20);
#pragma unroll
        for (int nt = 0; nt < 4; ++nt) {
          short8 bh = ldg_frag(wb + vh, (nt * 64 + l) * 8);
          short8 bl = ldg_frag(wb + vl, (nt * 64 + l) * 8);
          f32x4 acc = (f32x4){0.f, 0.f, 0.f, 0.f};
          MFMA3(acc, ah, al, bh, bl);
#pragma unroll
          for (int q = 0; q < 3; ++q) {
            const float4 av = *(const float4*)&att_s[w][i][nt * 3 + q][tb];
            op[i][q][nt] = fmaf(av.x, acc[0], op[i][q][nt]);
            op[i][q][nt] = fmaf(av.y, acc[1], op[i][q][nt]);
            op[i][q][nt] = fmaf(av.z, acc[2], op[i][q][nt]);
            op[i][q][nt] = fmaf(av.w, acc[3], op[i][q][nt]);
          }
        }
      }
#pragma unroll
      for (int i = 0; i < 2; ++i)
#pragma unroll
        for (int q = 0; q < 3; ++q)
#pragma unroll
          for (int nt = 0; nt < 4; ++nt) {
            float v = op[i][q][nt];
            v += __shfl_xor(v, 16); v += __shfl_xor(v, 32);
            if (l4 == 0) o_s[w][i * 3 + q][nt * 16 + l15] = v + bvf_s[lyr][nt * 16 + l15];
          }
    }
    WSYNC();

    // ---- O-proj + bias + residual + LN ----
    {
      const int oh = lyr ? WO2H : WO1H, ol = lyr ? WO2L : WO1L;
      f32x4 acc[4];
#pragma unroll
      for (int nt = 0; nt < 4; ++nt) acc[nt] = (f32x4){0.f, 0.f, 0.f, 0.f};
#pragma unroll
      for (int kt = 0; kt < 2; ++kt) {
        short8 ah, al;
        lds_frag(&o_s[w][min(l15, 5)][0], kt * 32 + l4 * 8, ah, al);
#pragma unroll
        for (int nt = 0; nt < 4; ++nt) {
          short8 bh = ldg_frag(wb + oh, ((kt * 4 + nt) * 64 + l) * 8);
          short8 bl = ldg_frag(wb + ol, ((kt * 4 + nt) * 64 + l) * 8);
          MFMA3(acc[nt], ah, al, bh, bl);
        }
      }
      float v[4][4];
#pragma unroll
      for (int nt = 0; nt < 4; ++nt)
#pragma unroll
        for (int reg = 0; reg < 4; ++reg) {
          const int r = l4 * 4 + reg, rr = min(r, 5);
          const int d = nt * 16 + l15;
          float resid;
          if (lyr == 0) {
            const int qq = rr - 3 * (rr >= 3);
            resid = qemb_s[qq * 64 + d];
          } else {
            resid = xq1[nt][reg];
          }
          v[nt][reg] = acc[nt][reg] + bias4_s[lyr][d] + resid;
        }
      ln_write(v, nrm_s[lyr * 2], nrm_s[lyr * 2 + 1], x_s[w],
               (lyr == 0) ? xq1 : xq2, l15, l4);
    }
    WSYNC();

    if (lyr == 0) {
      // ---- Q2 = x1 @ wq2 + bq2 -> o_s ----
      {
        f32x4 acc[4];
#pragma unroll
        for (int nt = 0; nt < 4; ++nt) acc[nt] = (f32x4){0.f, 0.f, 0.f, 0.f};
#pragma unroll
        for (int kt = 0; kt < 2; ++kt) {
          short8 ah, al;
          lds_frag(&x_s[w][min(l15, 5)][0], kt * 32 + l4 * 8, ah, al);
#pragma unroll
          for (int nt = 0; nt < 4; ++nt) {
            short8 bh = ldg_frag(wb + WQ2H, ((kt * 4 + nt) * 64 + l) * 8);
            short8 bl = ldg_frag(wb + WQ2L, ((kt * 4 + nt) * 64 + l) * 8);
            MFMA3(acc[nt], ah, al, bh, bl);
          }
        }
#pragma unroll
        for (int nt = 0; nt < 4; ++nt)
#pragma unroll
          for (int reg = 0; reg < 4; ++reg) {
            const int r = l4 * 4 + reg;
            if (r < 6) o_s[w][r][nt * 16 + l15] = acc[nt][reg] + bias4_s[2][nt * 16 + l15];
          }
      }
      WSYNC();
      // ---- g2 = q2 (head-masked) @ (SCALE*Wkf2^T) -> g2_s ----
      {
        f32x4 ga[2][2];
#pragma unroll
        for (int mt = 0; mt < 2; ++mt)
#pragma unroll
          for (int nt = 0; nt < 2; ++nt) ga[mt][nt] = (f32x4){0.f, 0.f, 0.f, 0.f};
#pragma unroll
        for (int mt = 0; mt < 2; ++mt) {
          const int arow = min(mt * 16 + l15, 23);
          const int ia = arow >= 12;
          const int hqa = arow - 12 * ia;
          const int h = (hqa * 11) >> 5;
          const int qa = hqa - 3 * h;
          const float* qrow = &o_s[w][ia * 3 + qa][0];
#pragma unroll
          for (int kt = 0; kt < 2; ++kt) {
            short8 ah, al;
            lds_frag(qrow, kt * 32 + l4 * 8, ah, al);
            const bool match = (kt * 2 + (l4 >> 1)) == h;
            if (!match) {
              const short8 z = {0, 0, 0, 0, 0, 0, 0, 0};
              ah = z; al = z;
            }
#pragma unroll
            for (int nt = 0; nt < 2; ++nt) {
              short8 bh = ldg_frag(wb + WKT2H, ((kt * 2 + nt) * 64 + l) * 8);
              short8 bl = ldg_frag(wb + WKT2L, ((kt * 2 + nt) * 64 + l) * 8);
              MFMA3(ga[mt][nt], ah, al, bh, bl);
            }
          }
        }
#pragma unroll
        for (int mt = 0; mt < 2; ++mt)
#pragma unroll
          for (int nt = 0; nt < 2; ++nt)
#pragma unroll
            for (int reg = 0; reg < 4; ++reg) {
              const int row = mt * 16 + l4 * 4 + reg;
              if (row < 24) {
                const int ia = row >= 12;
                g2_s[w][ia][row - 12 * ia][nt * 16 + l15] = ga[mt][nt][reg];
              }
            }
      }
      WSYNC();
    }
  }

  // ---- FFN1: f = relu(x2 @ w1 + b1) -> overlay a_s ----
  float* fbuf = (float*)a_s[w];
  {
    f32x4 acc[8];
#pragma unroll
    for (int nt = 0; nt < 8; ++nt) acc[nt] = (f32x4){0.f, 0.f, 0.f, 0.f};
#pragma unroll
    for (int kt = 0; kt < 2; ++kt) {
      short8 ah, al;
      lds_frag(&x_s[w][min(l15, 5)][0], kt * 32 + l4 * 8, ah, al);
#pragma unroll
      for (int nt = 0; nt < 8; ++nt) {
        short8 bh = ldg_frag(wb + F1H, ((kt * 8 + nt) * 64 + l) * 8);
        short8 bl = ldg_frag(wb + F1L, ((kt * 8 + nt) * 64 + l) * 8);
        MFMA3(acc[nt], ah, al, bh, bl);
      }
    }
#pragma unroll
    for (int nt = 0; nt < 8; ++nt)
#pragma unroll
      for (int reg = 0; reg < 4; ++reg) {
        const int r = l4 * 4 + reg;
        if (r < 6) {
          const int d = nt * 16 + l15;
          fbuf[r * 132 + d] = fmaxf(acc[nt][reg] + fb1_s[d], 0.f);
        }
      }
  }
  WSYNC();

  // ---- FFN2 + residual + LN3 -> x_s ----
  {
    f32x4 acc[4];
#pragma unroll
    for (int nt = 0; nt < 4; ++nt) acc[nt] = (f32x4){0.f, 0.f, 0.f, 0.f};
#pragma unroll
    for (int kt = 0; kt < 4; ++kt) {
      short8 ah, al;
      lds_frag(&fbuf[min(l15, 5) * 132], kt * 32 + l4 * 8, ah, al);
#pragma unroll
      for (int nt = 0; nt < 4; ++nt) {
        short8 bh = ldg_frag(wb + F2H, ((kt * 4 + nt) * 64 + l) * 8);
        short8 bl = ldg_frag(wb + F2L, ((kt * 4 + nt) * 64 + l) * 8);
        MFMA3(acc[nt], ah, al, bh, bl);
      }
    }
    float v[4][4];
#pragma unroll
    for (int nt = 0; nt < 4; ++nt)
#pragma unroll
      for (int reg = 0; reg < 4; ++reg)
        v[nt][reg] = acc[nt][reg] + bias4_s[3][nt * 16 + l15] + xq2[nt][reg];
    ln_write(v, nrm_s[4], nrm_s[5], x_s[w], xq3, l15, l4);
    (void)xq3;
  }
  WSYNC();

  // ---- head1: y = relu(x3 @ op_w1 + op_b1) -> o_s ----
  {
    f32x4 acc[2];
#pragma unroll
    for (int nt = 0; nt < 2; ++nt) acc[nt] = (f32x4){0.f, 0.f, 0.f, 0.f};
#pragma unroll
    for (int kt = 0; kt < 2; ++kt) {
      short8 ah, al;
      lds_frag(&x_s[w][min(l15, 5)][0], kt * 32 + l4 * 8, ah, al);
#pragma unroll
      for (int nt = 0; nt < 2; ++nt) {
        short8 bh = ldg_frag(wb + OP1H, ((kt * 2 + nt) * 64 + l) * 8);
        short8 bl = ldg_frag(wb + OP1L, ((kt * 2 + nt) * 64 + l) * 8);
        MFMA3(acc[nt], ah, al, bh, bl);
      }
    }
#pragma unroll
    for (int nt = 0; nt < 2; ++nt)
#pragma unroll
      for (int reg = 0; reg < 4; ++reg) {
        const int r = l4 * 4 + reg;
        if (r < 6) o_s[w][r][nt * 16 + l15] = fmaxf(acc[nt][reg] + opb1_s[nt * 16 + l15], 0.f);
      }
  }
  WSYNC();

  // ---- head2 ----
  if (l < 12) {
    const int r = l >> 1, e = l & 1;
    float acc = opb2_s[e];
#pragma unroll
    for (int m = 0; m < 32; ++m) acc = fmaf(o_s[w][r][m], opw2_s[m * 2 + e], acc);
    const int i = r >= 3, q = r - 3 * i;
    p.out[(itemBase + i) * 6 + q * 2 + e] = acc;
  }
}

extern "C" void kernel_launch(void* const* d_in, const int* in_sizes, int n_in,
                              void* d_out, int out_size, void* d_ws, size_t ws_size,
                              hipStream_t stream) {
  const float* in[40];
  for (int i = 0; i < n_in && i < 40; ++i) in[i] = (const float*)d_in[i];

  const float *a1_wq, *a1_wk, *a1_wv, *a1_wo, *a1_bq, *a1_bk, *a1_bv, *a1_bo;
  const float *a2_wq, *a2_wk, *a2_wv, *a2_wo, *a2_bq, *a2_bk, *a2_bv, *a2_bo;
  if (in_sizes[8] == 4096) {
    a1_wq = in[7];  a1_wk = in[8];  a1_wv = in[9];  a1_wo = in[10];
    a1_bq = in[11]; a1_bk = in[12]; a1_bv = in[13]; a1_bo = in[14];
    a2_wq = in[15]; a2_wk = in[16]; a2_wv = in[17]; a2_wo = in[18];
    a2_bq = in[19]; a2_bk = in[20]; a2_bv = in[21]; a2_bo = in[22];
  } else {
    a1_wq = in[7];  a1_bq = in[8];  a1_wk = in[9];  a1_bk = in[10];
    a1_wv = in[11]; a1_bv = in[12]; a1_wo = in[13]; a1_bo = in[14];
    a2_wq = in[15]; a2_bq = in[16]; a2_wk = in[17]; a2_bk = in[18];
    a2_wv = in[19]; a2_bv = in[20]; a2_wo = in[21]; a2_bo = in[22];
  }
  (void)a1_bk; (void)a2_bk;  // K biases cancel in softmax

  float* wsf = (float*)d_ws;
  unsigned short* wsb = (unsigned short*)d_ws;

  prepA_kernel<<<34, 256, 0, stream>>>(in[5], in[6], a1_wk, a2_wk, a1_wv, a2_wv,
                                       a1_bv, a2_bv, in[2], a1_wq, a1_bq, wsf);
  prepB_kernel<<<73, 512, 0, stream>>>(wsf, wsb, a2_wq, a1_wo, a2_wo,
                                       in[23], in[25], in[33]);

  Params p;
  p.tl = in[0]; p.tr = in[1]; p.qemb = in[2];
  p.ip_w1 = in[3]; p.ip_b1 = in[4];
  p.bq2 = a2_bq; p.bo1 = a1_bo; p.bo2 = a2_bo;
  p.fb1 = in[24]; p.fb2 = in[26];
  p.opb1 = in[34]; p.opw2 = in[35]; p.opb2 = in[36];
  p.n1g = in[27]; p.n1b = in[28]; p.n2g = in[29]; p.n2b = in[30];
  p.n3g = in[31]; p.n3b = in[32];
  p.wsf = wsf; p.wsb = wsb;
  p.out = (float*)d_out;

  planner_kernel<<<4096, 256, 0, stream>>>(p);
}

// Round 6
// 238.366 us; speedup vs baseline: 1.9705x; 1.9705x over previous
//
#include <hip/hip_runtime.h>
#include <math.h>

#define SCALE 0.36067376022224085f  // 0.25 * log2(e): folded attn scale for exp2-domain softmax

// ws float offsets
#define WVF1F 0      // [32][64] folded ip_w2@wv (layer1)
#define WVF2F 2048   // [32][64] layer2
#define WKT2F 4096   // [64][32] transposed folded ip_w2@wk2, * SCALE
#define G1F   6144   // [12][32] g1 (layer-1 score weights)
#define BVF1F 6528   // [64] folded v bias layer1
#define BVF2F 6592   // [64] layer2
// packed float4 weight layouts: P*[jc*4d_stride + d*4 + r] = W[(jc*4+r)*D + d]
#define PQ2   6656   // wq2    16jc x 64d -> 4096
#define PO1   10752  // wo1    4096
#define PO2   14848  // wo2    4096
#define PV1   18944  // folded Wv1  8jc x 64d -> 2048
#define PV2   20992  // folded Wv2  2048
#define PF1   23040  // ffn_w1 16jc x 128d -> 8192
#define PF2   31232  // ffn_w2 32mc x 64d -> 8192
#define POP1  39424  // op_w1  16jc x 32d -> 2048
// total 41472 floats

#define WSYNC() do { asm volatile("s_waitcnt lgkmcnt(0)" ::: "memory"); __builtin_amdgcn_wave_barrier(); } while (0)

struct Params {
  const float* tl; const float* tr; const float* qemb;
  const float* ip_w1; const float* ip_b1;
  const float* bq2;
  const float* bo1; const float* bo2;
  const float* ffn_b1; const float* ffn_b2;
  const float* n1_g; const float* n1_b;
  const float* n2_g; const float* n2_b;
  const float* n3_g; const float* n3_b;
  const float* op_b1;
  const float* op_w2; const float* op_b2;
  const float* ws;
  float* out;
};

// Fold ip_w2 @ wv (both layers), transposed+scaled ip_w2 @ wk2, and folded v-biases.
__global__ void prep1_kernel(const float* ip_w2, const float* ip_b2,
                             const float* wk2, const float* wv1, const float* wv2,
                             const float* bv1, const float* bv2, float* ws) {
  const int bid = blockIdx.x, tid = threadIdx.x;
  if (bid < 24) {
    const int idx = bid * 256 + tid;      // 0..6143
    const int mat = idx >> 11;
    const int rem = idx & 2047;
    const int j = rem >> 6, c = rem & 63;
    const float* W = (mat == 0) ? wv1 : (mat == 1) ? wv2 : wk2;
    float acc = 0.f;
    for (int m = 0; m < 64; ++m) acc = fmaf(ip_w2[j * 64 + m], W[m * 64 + c], acc);
    if (mat == 0)      ws[WVF1F + j * 64 + c] = acc;
    else if (mat == 1) ws[WVF2F + j * 64 + c] = acc;
    else               ws[WKT2F + c * 32 + j] = acc * SCALE;   // transposed
  } else if (tid < 128) {
    const int l = tid >> 6, d = tid & 63;
    const float* bv = l ? bv2 : bv1;
    const float* wv = l ? wv2 : wv1;
    float acc = bv[d];
    for (int m = 0; m < 64; ++m) acc = fmaf(ip_b2[m], wv[m * 64 + d], acc);
    ws[(l ? BVF2F : BVF1F) + d] = acc;
  }
}

// g1[h*3+q][j] = SCALE * sum_d Wkf1[j][h*16+d] * q1[q][h*16+d]; q1 = qemb@wq1+bq1
__global__ void prep2_kernel(const float* ip_w2, const float* wk1,
                             const float* qemb, const float* wq1, const float* bq1,
                             float* ws) {
  __shared__ float wkf[32][64];
  __shared__ float q1[3][64];
  const int tid = threadIdx.x;   // block of 384
  for (int e = tid; e < 2048; e += 384) {
    const int j = e >> 6, c = e & 63;
    float acc = 0.f;
    for (int m = 0; m < 64; ++m) acc = fmaf(ip_w2[j * 64 + m], wk1[m * 64 + c], acc);
    wkf[j][c] = acc;
  }
  if (tid < 192) {
    const int q = tid >> 6, d = tid & 63;
    float acc = bq1[d];
    for (int e = 0; e < 64; ++e) acc = fmaf(qemb[q * 64 + e], wq1[e * 64 + d], acc);
    q1[q][d] = acc;
  }
  __syncthreads();
  {
    const int r = tid >> 5, j = tid & 31;   // r = h*3+q, 12 rows -> tid<384
    const int h = r / 3, q = r - h * 3;
    float acc = 0.f;
    for (int d = 0; d < 16; ++d) acc = fmaf(wkf[j][h * 16 + d], q1[q][h * 16 + d], acc);
    ws[G1F + r * 32 + j] = acc * SCALE;
  }
}

// Pack projection weights into [jc][d][4] float4 layout so the hot kernel
// issues one global_load_dwordx4 per 12-16 FMAs (was 4 scalar loads + addr math).
__global__ void prepC_kernel(float* ws,
                             const float* wq2, const float* wo1, const float* wo2,
                             const float* fw1, const float* fw2, const float* opw1) {
  const int e = blockIdx.x * 256 + threadIdx.x;   // 0..34815
  if (e >= 34816) return;
  float v; int dst;
  if (e < 4096) {                     // wq2: 16jc x 64d
    const int i = e, jc = i >> 8, rem = i & 255, d = rem >> 2, r = rem & 3;
    v = wq2[(jc * 4 + r) * 64 + d]; dst = PQ2 + i;
  } else if (e < 8192) {              // wo1
    const int i = e - 4096, jc = i >> 8, rem = i & 255, d = rem >> 2, r = rem & 3;
    v = wo1[(jc * 4 + r) * 64 + d]; dst = PO1 + i;
  } else if (e < 12288) {             // wo2
    const int i = e - 8192, jc = i >> 8, rem = i & 255, d = rem >> 2, r = rem & 3;
    v = wo2[(jc * 4 + r) * 64 + d]; dst = PO2 + i;
  } else if (e < 14336) {             // folded Wv1: 8jc x 64d (reads prep1 output)
    const int i = e - 12288, jc = i >> 8, rem = i & 255, d = rem >> 2, r = rem & 3;
    v = ws[WVF1F + (jc * 4 + r) * 64 + d]; dst = PV1 + i;
  } else if (e < 16384) {             // folded Wv2
    const int i = e - 14336, jc = i >> 8, rem = i & 255, d = rem >> 2, r = rem & 3;
    v = ws[WVF2F + (jc * 4 + r) * 64 + d]; dst = PV2 + i;
  } else if (e < 24576) {             // ffn_w1: 16jc x 128d
    const int i = e - 16384, jc = i >> 9, rem = i & 511, d = rem >> 2, r = rem & 3;
    v = fw1[(jc * 4 + r) * 128 + d]; dst = PF1 + i;
  } else if (e < 32768) {             // ffn_w2: 32mc x 64d
    const int i = e - 24576, mc = i >> 8, rem = i & 255, d = rem >> 2, r = rem & 3;
    v = fw2[(mc * 4 + r) * 64 + d]; dst = PF2 + i;
  } else {                            // op_w1: 16jc x 32d
    const int i = e - 32768, jc = i >> 7, rem = i & 127, d = rem >> 2, r = rem & 3;
    v = opw1[(jc * 4 + r) * 32 + d]; dst = POP1 + i;
  }
  ws[dst] = v;
}

// __launch_bounds__(256) ONLY: forcing (256,5) caused a 48-VGPR budget -> scratch
// spills -> HBM-bound. Natural allocation (~80 VGPR) keeps good occupancy via LDS.
__global__ __launch_bounds__(256) void planner_kernel(Params p) {
  const int w = threadIdx.x >> 6;
  const int lane = threadIdx.x & 63;
  const int item = blockIdx.x * 4 + w;

  __shared__ __align__(16) float g1_s[12][36];       // block-shared
  __shared__ __align__(16) float a_s[4][20][36];     // relu acts; later overlaid by f1[3][136]
  __shared__ __align__(16) float att_s[4][12][24];   // raw scores -> exp; [.][20]=1/sum
  __shared__ __align__(16) float ch_s[4][12][36];    // att@a (normalized); also holds g2
  __shared__ __align__(16) float qx_s[4][3][68];     // q2 / attn-out o / y1
  __shared__ __align__(16) float x_s[4][3][68];      // residual stream
  __shared__ float pts_s[4][40];

  const float* ws = p.ws;

  for (int e = threadIdx.x; e < 384; e += 256)
    g1_s[e >> 5][e & 31] = ws[G1F + e];

  if (lane < 40)
    pts_s[w][lane] = (lane < 20) ? p.tl[item * 20 + lane] : p.tr[item * 20 + lane - 20];
  WSYNC();

  // a = relu(pts @ ip_w1 + ip_b1)   [20][32]
  {
    const int j = lane & 31, th = lane >> 5;
    const float w0 = p.ip_w1[j], w1 = p.ip_w1[32 + j], b = p.ip_b1[j];
#pragma unroll
    for (int i = 0; i < 10; ++i) {
      const int t = th * 10 + i;
      a_s[w][t][j] = fmaxf(fmaf(pts_s[w][2 * t], w0, fmaf(pts_s[w][2 * t + 1], w1, b)), 0.f);
    }
  }
  __syncthreads();  // covers g1_s (cross-wave) and a_s

  const int t3 = lane / 3;
  const int q3 = lane - t3 * 3;
  const int j32 = lane & 31, half = lane >> 5, hq0 = half * 6;
  const int h16 = lane >> 4;

  float xq[3];

#pragma unroll
  for (int l = 0; l < 2; ++l) {
    if (l == 1) {
      // Q2 projection: lane = channel, packed float4 weights
      float acc[3];
#pragma unroll
      for (int q = 0; q < 3; ++q) acc[q] = p.bq2[lane];
#pragma unroll
      for (int jc = 0; jc < 16; ++jc) {
        const float4 w4 = *(const float4*)&ws[PQ2 + jc * 256 + lane * 4];
#pragma unroll
        for (int q = 0; q < 3; ++q) {
          const float4 xv = *(const float4*)&x_s[w][q][jc * 4];
          acc[q] = fmaf(xv.x, w4.x, fmaf(xv.y, w4.y, fmaf(xv.z, w4.z, fmaf(xv.w, w4.w, acc[q]))));
        }
      }
#pragma unroll
      for (int q = 0; q < 3; ++q) qx_s[w][q][lane] = acc[q];
      WSYNC();
      // g2[h*3+q][j] = sum_D WkT2[D][j] * q2[q][D]   (SCALE folded in WkT2)
      {
        float g2[6] = {0, 0, 0, 0, 0, 0};
        const int D0 = half * 32;
#pragma unroll
        for (int dd = 0; dd < 32; ++dd) {
          const int D = D0 + dd;
          const float wk = ws[WKT2F + D * 32 + j32];
          const int hl = dd >> 4;
#pragma unroll
          for (int q = 0; q < 3; ++q)
            g2[hl * 3 + q] = fmaf(wk, qx_s[w][q][D], g2[hl * 3 + q]);
        }
#pragma unroll
        for (int k = 0; k < 6; ++k) ch_s[w][hq0 + k][j32] = g2[k];
      }
      WSYNC();
    }

    // scores: lane=(t,q), s[h] = sum_j a[t][j] * g[h*3+q][j]
    const float (*g)[36] = (l == 0) ? (const float (*)[36])g1_s : (const float (*)[36])ch_s[w];
    if (lane < 60) {
      float acc[4] = {0, 0, 0, 0};
#pragma unroll
      for (int jc = 0; jc < 8; ++jc) {
        const float4 av = *(const float4*)&a_s[w][t3][jc * 4];
#pragma unroll
        for (int h = 0; h < 4; ++h) {
          const float4 gv = *(const float4*)&g[h * 3 + q3][jc * 4];
          acc[h] = fmaf(av.x, gv.x, fmaf(av.y, gv.y, fmaf(av.z, gv.z, fmaf(av.w, gv.w, acc[h]))));
        }
      }
#pragma unroll
      for (int h = 0; h < 4; ++h) att_s[w][h * 3 + q3][t3] = acc[h];
    }
    WSYNC();

    // softmax rows (exp2 domain; scale folded upstream)
    if (lane < 12) {
      float m = -1e30f;
#pragma unroll
      for (int t = 0; t < 20; ++t) m = fmaxf(m, att_s[w][lane][t]);
      float s = 0.f;
#pragma unroll
      for (int t = 0; t < 20; ++t) {
        const float e = exp2f(att_s[w][lane][t] - m);
        att_s[w][lane][t] = e;
        s += e;
      }
      att_s[w][lane][20] = 1.f / s;
    }
    WSYNC();

    // ch[hq][j] = inv * sum_t att[hq][t] * a[t][j]; lane = (j, half of hq rows)
    {
      float c[6] = {0, 0, 0, 0, 0, 0};
#pragma unroll
      for (int tc = 0; tc < 5; ++tc) {
        float av[4];
#pragma unroll
        for (int r = 0; r < 4; ++r) av[r] = a_s[w][tc * 4 + r][j32];
#pragma unroll
        for (int k = 0; k < 6; ++k) {
          const float4 at = *(const float4*)&att_s[w][hq0 + k][tc * 4];
          c[k] = fmaf(at.x, av[0], fmaf(at.y, av[1], fmaf(at.z, av[2], fmaf(at.w, av[3], c[k]))));
        }
      }
#pragma unroll
      for (int k = 0; k < 6; ++k)
        ch_s[w][hq0 + k][j32] = c[k] * att_s[w][hq0 + k][20];
    }
    WSYNC();

    // o[q][d] = sum_j ch[h(d)*3+q][j] * Wvf[j][d] + bvf[d]  (packed Wv)
    {
      const int pv = l ? PV2 : PV1;
      const float bv = ws[(l ? BVF2F : BVF1F) + lane];
      float o[3] = {bv, bv, bv};
#pragma unroll
      for (int jc = 0; jc < 8; ++jc) {
        const float4 w4 = *(const float4*)&ws[pv + jc * 256 + lane * 4];
#pragma unroll
        for (int q = 0; q < 3; ++q) {
          const float4 cv = *(const float4*)&ch_s[w][h16 * 3 + q][jc * 4];
          o[q] = fmaf(cv.x, w4.x, fmaf(cv.y, w4.y, fmaf(cv.z, w4.z, fmaf(cv.w, w4.w, o[q]))));
        }
      }
#pragma unroll
      for (int q = 0; q < 3; ++q) qx_s[w][q][lane] = o[q];
    }
    WSYNC();

    // O-proj + residual + LN  (packed wo)
    {
      const int po = l ? PO2 : PO1;
      const float* bo = l ? p.bo2 : p.bo1;
      const float* gg = l ? p.n2_g : p.n1_g;
      const float* gb = l ? p.n2_b : p.n1_b;
      float acc[3];
#pragma unroll
      for (int q = 0; q < 3; ++q)
        acc[q] = bo[lane] + (l ? x_s[w][q][lane] : p.qemb[q * 64 + lane]);
#pragma unroll
      for (int jc = 0; jc < 16; ++jc) {
        const float4 w4 = *(const float4*)&ws[po + jc * 256 + lane * 4];
#pragma unroll
        for (int q = 0; q < 3; ++q) {
          const float4 ov = *(const float4*)&qx_s[w][q][jc * 4];
          acc[q] = fmaf(ov.x, w4.x, fmaf(ov.y, w4.y, fmaf(ov.z, w4.z, fmaf(ov.w, w4.w, acc[q]))));
        }
      }
      const float gv = gg[lane], bv = gb[lane];
#pragma unroll
      for (int q = 0; q < 3; ++q) {
        const float v = acc[q];
        float s = v;
#pragma unroll
        for (int m = 32; m >= 1; m >>= 1) s += __shfl_xor(s, m);
        const float mu = s * (1.f / 64.f);
        const float d = v - mu;
        float s2 = d * d;
#pragma unroll
        for (int m = 32; m >= 1; m >>= 1) s2 += __shfl_xor(s2, m);
        const float inv = rsqrtf(s2 * (1.f / 64.f) + 1e-5f);
        const float xn = fmaf(d * inv, gv, bv);
        xq[q] = xn;
        x_s[w][q][lane] = xn;
      }
    }
    WSYNC();
  }

  // FFN1: f1 = relu(x2 @ w1 + b1) -> overlay on a_s  (packed ffn_w1)
  float* f1p = (float*)a_s[w];
  {
    float a0[3], a1[3];
    const float b0 = p.ffn_b1[lane], b1 = p.ffn_b1[64 + lane];
#pragma unroll
    for (int q = 0; q < 3; ++q) { a0[q] = b0; a1[q] = b1; }
#pragma unroll
    for (int jc = 0; jc < 16; ++jc) {
      const float4 w04 = *(const float4*)&ws[PF1 + jc * 512 + lane * 4];
      const float4 w14 = *(const float4*)&ws[PF1 + jc * 512 + 256 + lane * 4];
#pragma unroll
      for (int q = 0; q < 3; ++q) {
        const float4 xv = *(const float4*)&x_s[w][q][jc * 4];
        a0[q] = fmaf(xv.x, w04.x, fmaf(xv.y, w04.y, fmaf(xv.z, w04.z, fmaf(xv.w, w04.w, a0[q]))));
        a1[q] = fmaf(xv.x, w14.x, fmaf(xv.y, w14.y, fmaf(xv.z, w14.z, fmaf(xv.w, w14.w, a1[q]))));
      }
    }
#pragma unroll
    for (int q = 0; q < 3; ++q) {
      f1p[q * 136 + lane] = fmaxf(a0[q], 0.f);
      f1p[q * 136 + 64 + lane] = fmaxf(a1[q], 0.f);
    }
  }
  WSYNC();

  // FFN2 + residual + LN3  (packed ffn_w2)
  {
    float acc[3];
#pragma unroll
    for (int q = 0; q < 3; ++q) acc[q] = p.ffn_b2[lane] + xq[q];
#pragma unroll
    for (int mc = 0; mc < 32; ++mc) {
      const float4 w4 = *(const float4*)&ws[PF2 + mc * 256 + lane * 4];
#pragma unroll
      for (int q = 0; q < 3; ++q) {
        const float4 fv = *(const float4*)&f1p[q * 136 + mc * 4];
        acc[q] = fmaf(fv.x, w4.x, fmaf(fv.y, w4.y, fmaf(fv.z, w4.z, fmaf(fv.w, w4.w, acc[q]))));
      }
    }
    const float gv = p.n3_g[lane], bv = p.n3_b[lane];
#pragma unroll
    for (int q = 0; q < 3; ++q) {
      const float v = acc[q];
      float s = v;
#pragma unroll
      for (int m = 32; m >= 1; m >>= 1) s += __shfl_xor(s, m);
      const float mu = s * (1.f / 64.f);
      const float d = v - mu;
      float s2 = d * d;
#pragma unroll
      for (int m = 32; m >= 1; m >>= 1) s2 += __shfl_xor(s2, m);
      const float inv = rsqrtf(s2 * (1.f / 64.f) + 1e-5f);
      x_s[w][q][lane] = fmaf(d * inv, gv, bv);
    }
  }
  WSYNC();

  // head 1: y1 = relu(x3 @ op_w1 + op_b1) [3][32]  (packed op_w1)
  if (lane < 32) {
    float acc[3];
#pragma unroll
    for (int q = 0; q < 3; ++q) acc[q] = p.op_b1[lane];
#pragma unroll
    for (int jc = 0; jc < 16; ++jc) {
      const float4 w4 = *(const float4*)&ws[POP1 + jc * 128 + lane * 4];
#pragma unroll
      for (int q = 0; q < 3; ++q) {
        const float4 xv = *(const float4*)&x_s[w][q][jc * 4];
        acc[q] = fmaf(xv.x, w4.x, fmaf(xv.y, w4.y, fmaf(xv.z, w4.z, fmaf(xv.w, w4.w, acc[q]))));
      }
    }
#pragma unroll
    for (int q = 0; q < 3; ++q) qx_s[w][q][lane] = fmaxf(acc[q], 0.f);
  }
  WSYNC();

  if (lane < 6) {
    const int q = lane >> 1, e = lane & 1;
    float acc = p.op_b2[e];
#pragma unroll
    for (int m = 0; m < 32; ++m) acc = fmaf(qx_s[w][q][m], p.op_w2[m * 2 + e], acc);
    p.out[item * 6 + q * 2 + e] = acc;
  }
}

extern "C" void kernel_launch(void* const* d_in, const int* in_sizes, int n_in,
                              void* d_out, int out_size, void* d_ws, size_t ws_size,
                              hipStream_t stream) {
  const float* in[40];
  for (int i = 0; i < n_in && i < 40; ++i) in[i] = (const float*)d_in[i];

  const float *a1_wq, *a1_wk, *a1_wv, *a1_wo, *a1_bq, *a1_bk, *a1_bv, *a1_bo;
  const float *a2_wq, *a2_wk, *a2_wv, *a2_wo, *a2_bq, *a2_bk, *a2_bv, *a2_bo;
  if (in_sizes[8] == 4096) {
    a1_wq = in[7];  a1_wk = in[8];  a1_wv = in[9];  a1_wo = in[10];
    a1_bq = in[11]; a1_bk = in[12]; a1_bv = in[13]; a1_bo = in[14];
    a2_wq = in[15]; a2_wk = in[16]; a2_wv = in[17]; a2_wo = in[18];
    a2_bq = in[19]; a2_bk = in[20]; a2_bv = in[21]; a2_bo = in[22];
  } else {
    a1_wq = in[7];  a1_bq = in[8];  a1_wk = in[9];  a1_bk = in[10];
    a1_wv = in[11]; a1_bv = in[12]; a1_wo = in[13]; a1_bo = in[14];
    a2_wq = in[15]; a2_bq = in[16]; a2_wk = in[17]; a2_bk = in[18];
    a2_wv = in[19]; a2_bv = in[20]; a2_wo = in[21]; a2_bo = in[22];
  }
  (void)a1_bk; (void)a2_bk;  // K biases fold out of softmax exactly

  float* ws = (float*)d_ws;
  prep1_kernel<<<25, 256, 0, stream>>>(in[5], in[6], a2_wk, a1_wv, a2_wv, a1_bv, a2_bv, ws);
  prep2_kernel<<<1, 384, 0, stream>>>(in[5], a1_wk, in[2], a1_wq, a1_bq, ws);
  prepC_kernel<<<136, 256, 0, stream>>>(ws, a2_wq, a1_wo, a2_wo, in[23], in[25], in[33]);

  Params p;
  p.tl = in[0]; p.tr = in[1]; p.qemb = in[2];
  p.ip_w1 = in[3]; p.ip_b1 = in[4];
  p.bq2 = a2_bq;
  p.bo1 = a1_bo; p.bo2 = a2_bo;
  p.ffn_b1 = in[24]; p.ffn_b2 = in[26];
  p.n1_g = in[27]; p.n1_b = in[28]; p.n2_g = in[29]; p.n2_b = in[30];
  p.n3_g = in[31]; p.n3_b = in[32];
  p.op_b1 = in[34]; p.op_w2 = in[35]; p.op_b2 = in[36];
  p.ws = ws; p.out = (float*)d_out;

  planner_kernel<<<8192, 256, 0, stream>>>(p);
}